// Round 1
// baseline (921.174 us; speedup 1.0000x reference)
//
#include <hip/hip_runtime.h>
#include <math.h>

#define HID 256
#define BIGI (1 << 30)

// ---- workspace layout (4-byte units) ----
#define MM_OFF   0          // 64 images x 4 ints (xmin,xmax,ymin,ymax)
#define SRC_OFF  256        // 64 x 256 floats: pos2 (phase 1) then h1s (phase 2)
#define XG_OFF   16640      // 64 x 1024 floats: xg0 then xg1
// total = 82176 * 4 = 328,704 bytes

// ---- output layout (floats) ----
#define OUT_DELTAS 0       // (4,5,4)
#define OUT_PBB    80      // (4,5,4)
#define OUT_LOC    160     // (4,5,2)
#define OUT_SCL    200     // (4,5,2)
#define OUT_MF     240     // (4,16,256)
#define OUT_CONF   16624   // (4,5)
#define OUT_BBOX   16644   // (4,16,4)

// LSTM tiling: rows of whh resident in VGPRs vs streamed from L2
#define RK  88                    // register-resident k-rows (must be %4==0)
#define SKG ((256 - RK) / 4)      // streamed 4-row groups = 42

__device__ __forceinline__ float sigmoidf_(float x) { return 1.0f / (1.0f + expf(-x)); }

// ---------------- kernel 1: init minmax sentinels ----------------
__global__ void k_init(int* ws) {
    int tid = threadIdx.x;
    ws[MM_OFF + tid] = (tid & 1) ? -1 : BIGI;  // [BIG, -1, BIG, -1] per image
}

// ---------------- kernel 2: per-image mask min/max (unchanged) ----------------
// grid = 64 images * 32 chunks, block = 256. Each thread: 32 float4 = 512B.
__global__ __launch_bounds__(256) void k_minmax(const float4* __restrict__ pred,
                                                int* __restrict__ mm) {
    int img = blockIdx.x >> 5;
    int chunk = blockIdx.x & 31;
    int tid = threadIdx.x;
    int base = img * 262144 + chunk * 8192 + tid;
    int xmn = BIGI, xmx = -1, ymn = BIGI, ymx = -1;
#pragma unroll 4
    for (int i = 0; i < 32; ++i) {
        int idx4 = base + i * 256;
        float4 v = pred[idx4];
        int x = (idx4 << 2) & 1023;
        int y = (idx4 >> 8) & 1023;
        bool m0 = v.x > 0.5f, m1 = v.y > 0.5f, m2 = v.z > 0.5f, m3 = v.w > 0.5f;
        int cmn = m0 ? x : (m1 ? x + 1 : (m2 ? x + 2 : (m3 ? x + 3 : BIGI)));
        int cmx = m3 ? x + 3 : (m2 ? x + 2 : (m1 ? x + 1 : (m0 ? x : -1)));
        xmn = min(xmn, cmn);
        xmx = max(xmx, cmx);
        if (m0 | m1 | m2 | m3) { ymn = min(ymn, y); ymx = max(ymx, y); }
    }
    for (int off = 32; off > 0; off >>= 1) {
        xmn = min(xmn, __shfl_down(xmn, off));
        xmx = max(xmx, __shfl_down(xmx, off));
        ymn = min(ymn, __shfl_down(ymn, off));
        ymx = max(ymx, __shfl_down(ymx, off));
    }
    __shared__ int red[4][4];
    int wave = tid >> 6;
    if ((tid & 63) == 0) { red[0][wave] = xmn; red[1][wave] = xmx; red[2][wave] = ymn; red[3][wave] = ymx; }
    __syncthreads();
    if (tid == 0) {
        xmn = min(min(red[0][0], red[0][1]), min(red[0][2], red[0][3]));
        xmx = max(max(red[1][0], red[1][1]), max(red[1][2], red[1][3]));
        ymn = min(min(red[2][0], red[2][1]), min(red[2][2], red[2][3]));
        ymx = max(max(red[3][0], red[3][1]), max(red[3][2], red[3][3]));
        atomicMin(&mm[img * 4 + 0], xmn);
        atomicMax(&mm[img * 4 + 1], xmx);
        atomicMin(&mm[img * 4 + 2], ymn);
        atomicMax(&mm[img * 4 + 3], ymx);
    }
}

// ---------------- kernel 3: bbox + pos-MLP (64 wgs, one per image) ----------------
__global__ __launch_bounds__(256) void k_prep(const int* __restrict__ mm,
    const float* __restrict__ pe_w1, const float* __restrict__ pe_b1,
    const float* __restrict__ pe_w2, const float* __restrict__ pe_b2,
    float* __restrict__ pos2, float* __restrict__ out) {
    __shared__ float bb[4];
    __shared__ float p1[256];
    int w = blockIdx.x, tid = threadIdx.x;
    if (tid == 0) {
        int xmn = mm[w * 4 + 0], xmx = mm[w * 4 + 1];
        int ymn = mm[w * 4 + 2], ymx = mm[w * 4 + 3];
        float cx, cy, bw, bh;
        if (xmx >= 0) {
            cx = (float)(xmn + xmx) * (0.5f / 1024.0f);
            cy = (float)(ymn + ymx) * (0.5f / 1024.0f);
            bw = (float)(xmx - xmn) * (1.0f / 1024.0f);
            bh = (float)(ymx - ymn) * (1.0f / 1024.0f);
        } else { cx = 0.5f; cy = 0.5f; bw = 0.1f; bh = 0.1f; }
        bb[0] = cx; bb[1] = cy; bb[2] = bw; bb[3] = bh;
        out[OUT_BBOX + w * 4 + 0] = cx; out[OUT_BBOX + w * 4 + 1] = cy;
        out[OUT_BBOX + w * 4 + 2] = bw; out[OUT_BBOX + w * 4 + 3] = bh;
    }
    __syncthreads();
    {
        float v = bb[0] * pe_w1[tid] + bb[1] * pe_w1[256 + tid] +
                  bb[2] * pe_w1[512 + tid] + bb[3] * pe_w1[768 + tid] + pe_b1[tid];
        p1[tid] = fmaxf(v, 0.0f);
    }
    __syncthreads();
    float acc = pe_b2[tid];
#pragma unroll 4
    for (int k = 0; k < 256; ++k) acc += p1[k] * pe_w2[k * 256 + tid];
    pos2[w * 256 + tid] = fmaxf(acc, 0.0f);
}

// ---------------- kernel 4: xg = src @ wih + bih + bhh (64 wgs x 16 cols) ----------------
__global__ __launch_bounds__(256) void k_xg(const float* __restrict__ src,
    const float* __restrict__ wih, const float* __restrict__ bih,
    const float* __restrict__ bhh, float* __restrict__ xg) {
    __shared__ float s[64 * 256];
    int tid = threadIdx.x;
    for (int i = tid; i < 16384; i += 256) s[i] = src[i];
    __syncthreads();
    int cc = tid & 15, rq = tid >> 4;          // col-in-wg, row-quad
    int col = blockIdx.x * 16 + cc;
    float bias = bih[col] + bhh[col];          // fold both biases into xg
    float a0 = bias, a1 = bias, a2 = bias, a3 = bias;
    const float* s0 = s + rq * 4 * 256;
#pragma unroll 4
    for (int k = 0; k < 256; ++k) {
        float wv = wih[k * 1024 + col];
        a0 += s0[k] * wv;
        a1 += s0[256 + k] * wv;
        a2 += s0[512 + k] * wv;
        a3 += s0[768 + k] * wv;
    }
    int r0 = rq * 4;
    xg[(r0 + 0) * 1024 + col] = a0;
    xg[(r0 + 1) * 1024 + col] = a1;
    xg[(r0 + 2) * 1024 + col] = a2;
    xg[(r0 + 3) * 1024 + col] = a3;
}

// ---------------- kernel 5: LSTM recurrence, one wg per batch ----------------
// 4 wgs x 512 threads. Thread t owns gate cols 2t, 2t+1. whh rows [0,RK) live in
// VGPRs (176 regs), rows [RK,256) streamed from L2 each step (~672 KB, L2-resident).
// h broadcast via LDS float4 reads (same-address -> conflict-free). Only
// __syncthreads() per step -- no device-scope sync anywhere.
template <int LAYER>
__global__ __launch_bounds__(512, 2) void k_lstm(
    const float* __restrict__ whh, const float* __restrict__ xg,
    float* __restrict__ h1s, float* __restrict__ out,
    const int* __restrict__ mm,
    const float* __restrict__ mp_w1, const float* __restrict__ mp_b1,
    const float* __restrict__ mp_w2, const float* __restrict__ mp_b2,
    const float* __restrict__ mp_w3, const float* __restrict__ mp_b3,
    const float* __restrict__ cf_w1, const float* __restrict__ cf_b1,
    const float* __restrict__ cf_w2, const float* __restrict__ cf_b2) {
    __shared__ float4 h4buf[64];       // current h (256 floats)
    __shared__ float gates[1024];      // gate row; reused as heads scratch
    const int tid = threadIdx.x;
    const int b = blockIdx.x;
    float* hbufs = (float*)h4buf;

    // load register-resident weight rows: wreg[k] = whh[k][2t..2t+1]
    float2 wreg[RK];
    {
        const float2* w2 = (const float2*)whh;
#pragma unroll
        for (int k = 0; k < RK; ++k) wreg[k] = w2[k * 512 + tid];
    }
    float cstate = 0.0f;
    const float2* xg2 = (const float2*)xg;
    const float2* ws2 = (const float2*)(whh + RK * 1024);

    for (int t = 0; t < 16; ++t) {
        float2 a = xg2[(b * 16 + t) * 512 + tid];
        float accx = a.x, accy = a.y;
        if (t != 0) {  // h == 0 at t==0: skip recurrent term (and its weight stream)
#pragma unroll
            for (int k4 = 0; k4 < RK / 4; ++k4) {
                float4 h = h4buf[k4];
                float2 w0 = wreg[4 * k4 + 0], w1 = wreg[4 * k4 + 1];
                float2 w2r = wreg[4 * k4 + 2], w3 = wreg[4 * k4 + 3];
                accx += h.x * w0.x + h.y * w1.x + h.z * w2r.x + h.w * w3.x;
                accy += h.x * w0.y + h.y * w1.y + h.z * w2r.y + h.w * w3.y;
            }
#pragma unroll 4
            for (int g = 0; g < SKG; ++g) {
                float4 h = h4buf[RK / 4 + g];
                float2 w0 = ws2[(4 * g + 0) * 512 + tid];
                float2 w1 = ws2[(4 * g + 1) * 512 + tid];
                float2 w2r = ws2[(4 * g + 2) * 512 + tid];
                float2 w3 = ws2[(4 * g + 3) * 512 + tid];
                accx += h.x * w0.x + h.y * w1.x + h.z * w2r.x + h.w * w3.x;
                accy += h.x * w0.y + h.y * w1.y + h.z * w2r.y + h.w * w3.y;
            }
        }
        float2 g2; g2.x = accx; g2.y = accy;
        ((float2*)gates)[tid] = g2;
        __syncthreads();
        if (tid < 256) {
            float gi = gates[tid], gf = gates[256 + tid];
            float gg = gates[512 + tid], go = gates[768 + tid];
            float i_ = sigmoidf_(gi), f_ = sigmoidf_(gf);
            float g_ = tanhf(gg), o_ = sigmoidf_(go);
            cstate = f_ * cstate + i_ * g_;
            float h = o_ * tanhf(cstate);
            hbufs[tid] = h;
            if (LAYER == 0) h1s[(b * 16 + t) * 256 + tid] = h;
            else out[OUT_MF + (b * 16 + t) * 256 + tid] = h;
        }
        __syncthreads();
    }

    if (LAYER == 1) {  // heads for this batch; lh = hbufs (h at t=15)
        float* x1 = gates;         // 256
        float* c1 = gates + 256;   // 128
        float* x2 = gates + 384;   // 128
        float* dl = gates + 512;   // 20
        const float* lh = hbufs;
        if (tid < 256) {
            float a = mp_b1[tid];
#pragma unroll 4
            for (int k = 0; k < 256; ++k) a += lh[k] * mp_w1[k * 256 + tid];
            x1[tid] = fmaxf(a, 0.0f);
        } else if (tid < 384) {
            int j = tid - 256;
            float a = cf_b1[j];
#pragma unroll 4
            for (int k = 0; k < 256; ++k) a += lh[k] * cf_w1[k * 128 + j];
            c1[j] = fmaxf(a, 0.0f);
        }
        __syncthreads();
        if (tid < 128) {
            float a = mp_b2[tid];
#pragma unroll 4
            for (int k = 0; k < 256; ++k) a += x1[k] * mp_w2[k * 128 + tid];
            x2[tid] = fmaxf(a, 0.0f);
        } else if (tid < 133) {
            int j = tid - 128;
            float a = cf_b2[j];
#pragma unroll 4
            for (int k = 0; k < 128; ++k) a += c1[k] * cf_w2[k * 5 + j];
            out[OUT_CONF + b * 5 + j] = sigmoidf_(a);
        }
        __syncthreads();
        if (tid < 20) {
            float a = mp_b3[tid];
#pragma unroll 4
            for (int k = 0; k < 128; ++k) a += x2[k] * mp_w3[k * 20 + tid];
            dl[tid] = a;
            out[OUT_DELTAS + b * 20 + tid] = a;
        }
        __syncthreads();
        if (tid < 4) {  // cumsum of deltas onto last bbox (image b*16+15)
            int img = b * 16 + 15;
            int xmn = mm[img * 4 + 0], xmx = mm[img * 4 + 1];
            int ymn = mm[img * 4 + 2], ymx = mm[img * 4 + 3];
            float v;
            if (xmx >= 0) {
                if (tid == 0)      v = (float)(xmn + xmx) * (0.5f / 1024.0f);
                else if (tid == 1) v = (float)(ymn + ymx) * (0.5f / 1024.0f);
                else if (tid == 2) v = (float)(xmx - xmn) * (1.0f / 1024.0f);
                else               v = (float)(ymx - ymn) * (1.0f / 1024.0f);
            } else v = (tid < 2) ? 0.5f : 0.1f;
            float acc = v;
            for (int hh = 0; hh < 5; ++hh) {
                acc += dl[hh * 4 + tid];
                out[OUT_PBB + b * 20 + hh * 4 + tid] = acc;
                if (tid < 2) out[OUT_LOC + b * 10 + hh * 2 + tid] = acc;
                else out[OUT_SCL + b * 10 + hh * 2 + (tid - 2)] = acc;
            }
        }
    }
}

extern "C" void kernel_launch(void* const* d_in, const int* in_sizes, int n_in,
                              void* d_out, int out_size, void* d_ws, size_t ws_size,
                              hipStream_t stream) {
    (void)in_sizes; (void)n_in; (void)out_size; (void)ws_size;
    const float* pred = (const float*)d_in[1];  // d_in[0] = features (unused by reference)
    const float* pe_w1 = (const float*)d_in[2];
    const float* pe_b1 = (const float*)d_in[3];
    const float* pe_w2 = (const float*)d_in[4];
    const float* pe_b2 = (const float*)d_in[5];
    const float* wih0 = (const float*)d_in[6];
    const float* whh0 = (const float*)d_in[7];
    const float* bih0 = (const float*)d_in[8];
    const float* bhh0 = (const float*)d_in[9];
    const float* wih1 = (const float*)d_in[10];
    const float* whh1 = (const float*)d_in[11];
    const float* bih1 = (const float*)d_in[12];
    const float* bhh1 = (const float*)d_in[13];
    const float* mp_w1 = (const float*)d_in[14];
    const float* mp_b1 = (const float*)d_in[15];
    const float* mp_w2 = (const float*)d_in[16];
    const float* mp_b2 = (const float*)d_in[17];
    const float* mp_w3 = (const float*)d_in[18];
    const float* mp_b3 = (const float*)d_in[19];
    const float* cf_w1 = (const float*)d_in[20];
    const float* cf_b1 = (const float*)d_in[21];
    const float* cf_w2 = (const float*)d_in[22];
    const float* cf_b2 = (const float*)d_in[23];
    float* out = (float*)d_out;
    int* wsi = (int*)d_ws;
    float* wsf = (float*)d_ws;

    hipLaunchKernelGGL(k_init, dim3(1), dim3(256), 0, stream, wsi);
    hipLaunchKernelGGL(k_minmax, dim3(64 * 32), dim3(256), 0, stream,
                       (const float4*)pred, wsi + MM_OFF);
    hipLaunchKernelGGL(k_prep, dim3(64), dim3(256), 0, stream,
                       wsi + MM_OFF, pe_w1, pe_b1, pe_w2, pe_b2,
                       wsf + SRC_OFF, out);
    // xg0 = pos2 @ wih0 + bih0 + bhh0
    hipLaunchKernelGGL(k_xg, dim3(64), dim3(256), 0, stream,
                       wsf + SRC_OFF, wih0, bih0, bhh0, wsf + XG_OFF);
    // layer-0 recurrence -> h1s (overwrites pos2 region, which is dead now)
    hipLaunchKernelGGL(HIP_KERNEL_NAME(k_lstm<0>), dim3(4), dim3(512), 0, stream,
                       whh0, wsf + XG_OFF, wsf + SRC_OFF, out, wsi + MM_OFF,
                       mp_w1, mp_b1, mp_w2, mp_b2, mp_w3, mp_b3,
                       cf_w1, cf_b1, cf_w2, cf_b2);
    // xg1 = h1s @ wih1 + bih1 + bhh1 (overwrites xg0, dead)
    hipLaunchKernelGGL(k_xg, dim3(64), dim3(256), 0, stream,
                       wsf + SRC_OFF, wih1, bih1, bhh1, wsf + XG_OFF);
    // layer-1 recurrence + heads
    hipLaunchKernelGGL(HIP_KERNEL_NAME(k_lstm<1>), dim3(4), dim3(512), 0, stream,
                       whh1, wsf + XG_OFF, wsf + SRC_OFF, out, wsi + MM_OFF,
                       mp_w1, mp_b1, mp_w2, mp_b2, mp_w3, mp_b3,
                       cf_w1, cf_b1, cf_w2, cf_b2);
}